// Round 5
// baseline (1753.158 us; speedup 1.0000x reference)
//
#include <hip/hip_runtime.h>
#include <math.h>
#include <stdint.h>

#define B_ 4096
#define N_ 32768
#define D_ 1024

#define BM 128
#define BN 128
#define NT 2
#define NCHUNK 128     // N_ / (BN*NT)
#define KTOT 32        // D_ / 32
#define QG (B_ / 16)   // 256 q-row groups
#define KG (N_ / 16)   // 2048 k-row groups

typedef __attribute__((ext_vector_type(8))) short short8;
typedef __attribute__((ext_vector_type(4))) float f4;
typedef unsigned short u16;

__device__ __forceinline__ u16 bf16_rn(float x) {
    uint32_t u = __float_as_uint(x);
    u += 0x7fffu + ((u >> 16) & 1u);
    return (u16)(u >> 16);
}

// fp32 -> (hi, lo) bf16 pair, both RN. Dropped residual ~2^-18 |x|.
__device__ __forceinline__ void split4(f4 v, uint2& hpack, uint2& lpack) {
    u16 h[4], l[4];
    #pragma unroll
    for (int e = 0; e < 4; ++e) {
        float x = v[e];
        u16 hb = bf16_rn(x);
        float hf = __uint_as_float(((uint32_t)hb) << 16);
        h[e] = hb;
        l[e] = bf16_rn(x - hf);
    }
    hpack.x = (uint32_t)h[0] | ((uint32_t)h[1] << 16);
    hpack.y = (uint32_t)h[2] | ((uint32_t)h[3] << 16);
    lpack.x = (uint32_t)l[0] | ((uint32_t)l[1] << 16);
    lpack.y = (uint32_t)l[2] | ((uint32_t)l[3] << 16);
}

// async global -> LDS, 16B per lane. LDS dest is wave-uniform base + lane*16.
__device__ __forceinline__ void g2l16(const void* g, void* l) {
    __builtin_amdgcn_global_load_lds(
        (const __attribute__((address_space(1))) char*)(uintptr_t)g,
        (__attribute__((address_space(3))) char*)(uint32_t)(uintptr_t)l,
        16, 0, 0);
}

// ---------------------------------------------------------------------------
// Kernel 1 (fused norm + pack, VERIFIED rounds 1/3): each thread loads exactly
// the 64 floats it will pack (kept in registers), block computes the 16 row
// inv-norms via shfl + a 4x16 LDS patch, then normalizes + splits into bf16
// hi/lo planes, packed FRAG-LINEAR: chunk(kt, g) = 1KB covering rows
// 16g..16g+15, k = 32kt..32kt+31, MFMA lane order: lane l holds
// (m = l&15, k = (l>>4)*8 + 0..7), 16B/lane.
// Plane layout: [kt][group][512 u16]. Also zeroes the var slot of d_out.
// ---------------------------------------------------------------------------
__global__ __launch_bounds__(256) void pack_kernel(
    const float* __restrict__ q, const float* __restrict__ k,
    float* __restrict__ invq, float* __restrict__ invk,
    u16* __restrict__ qhi, u16* __restrict__ qlo,
    u16* __restrict__ khi, u16* __restrict__ klo,
    float* __restrict__ out)
{
    const int g = blockIdx.x;                 // 0..(B_+N_)/16-1
    const int lane = threadIdx.x & 63;
    const int w = threadIdx.x >> 6;

    const float* src; float* invdst;
    u16 *dhi, *dlo; int groups, gg;
    if (g < B_ / 16) { src = q; invdst = invq; dhi = qhi; dlo = qlo; groups = QG; gg = g; }
    else { src = k; invdst = invk; dhi = khi; dlo = klo; groups = KG; gg = g - B_ / 16; }

    const int row = gg * 16 + (lane & 15);
    const int kofs = (lane >> 4) * 8;
    const float* rp = src + (size_t)row * D_;

    // phase 1: load this thread's 64 elements (8 kts), partial sum-of-squares
    f4 v0[8], v1[8];
    float s = 0.f;
    #pragma unroll
    for (int u = 0; u < 8; ++u) {
        const int kt = w + u * 4;
        v0[u] = *(const f4*)(rp + kt * 32 + kofs);
        v1[u] = *(const f4*)(rp + kt * 32 + kofs + 4);
        #pragma unroll
        for (int e = 0; e < 4; ++e) {
            s = fmaf(v0[u][e], v0[u][e], s);
            s = fmaf(v1[u][e], v1[u][e], s);
        }
    }
    // reduce over the 4 quads of this wave (same l16 = same row)
    s += __shfl_xor(s, 16);
    s += __shfl_xor(s, 32);
    __shared__ float red[4][16];
    if ((lane >> 4) == 0) red[w][lane & 15] = s;
    __syncthreads();
    const float tot = red[0][lane & 15] + red[1][lane & 15]
                    + red[2][lane & 15] + red[3][lane & 15];
    const float scale = 1.0f / fmaxf(sqrtf(tot), 1e-12f);
    if (w == 0 && lane < 16) invdst[gg * 16 + lane] = scale;

    // phase 2: scale + split + frag-linear store (data still in registers)
    #pragma unroll
    for (int u = 0; u < 8; ++u) {
        const int kt = w + u * 4;
        f4 a = v0[u] * scale, b = v1[u] * scale;
        uint2 h0, l0, h1, l1;
        split4(a, h0, l0);
        split4(b, h1, l1);
        const size_t cbase = ((size_t)kt * groups + gg) * 512 + lane * 8;
        uint4 hh = {h0.x, h0.y, h1.x, h1.y};
        uint4 ll = {l0.x, l0.y, l1.x, l1.y};
        *(uint4*)(dhi + cbase) = hh;
        *(uint4*)(dlo + cbase) = ll;
    }
    if (g == 0 && threadIdx.x == 0) out[(size_t)B_ * D_] = 0.0f;
}

// ---------------------------------------------------------------------------
// Kernel 2: split-bf16 MFMA sim GEMM, 16x16x32 shape (verified round-0
// barrier/DMA template). LDS stages only A-hi, B-hi, B-lo (24KB/slab,
// 2 x 24KB = 48KB -> 3 blocks/CU, 12 waves). A-lo frags are per-lane global
// loads from qlo (L2-resident, 2MB/XCD), issued right after the barrier
// (BEFORE the kt+1 DMAs, so their counted vmcnt wait leaves the prefetch in
// flight) and consumed only by the LAST 16 of the 48 MFMAs (~155 cyc slack
// covers L2 latency). All register loads consumed within their own barrier
// window — no cross-barrier register lifetimes.
// ---------------------------------------------------------------------------
__global__ __launch_bounds__(256, 3) void sim_stats_kernel(
    const u16* __restrict__ qhi, const u16* __restrict__ qlo,
    const u16* __restrict__ khi, const u16* __restrict__ klo,
    float* __restrict__ partials)
{
    __shared__ __align__(16) char smem[49152];   // 2 x 24KB slabs; scan aliased

    const int tid = threadIdx.x;
    const int lane = tid & 63;
    const int w = tid >> 6;
    const int wm = w >> 1, wn = w & 1;
    const int quad = lane >> 4;
    const int l16 = lane & 15;
    const int mtile = blockIdx.x;
    const int chunk = blockIdx.y;
    const int b0 = mtile * BM;

    const int aG0 = b0 >> 4;                  // block A group base (8 groups)
    const int aG0w = aG0 + wm * 4;            // this wave's A group base

    float (*scan)[68] = (float(*)[68])smem;

    float r_sum = 0.f, r_sq = 0.f, r_m1 = -INFINITY, r_m2 = -INFINITY;
    int r_i1 = 0x7fffffff, r_i2 = 0x7fffffff;

    const f4 zf = {0.f, 0.f, 0.f, 0.f};

    for (int nt = 0; nt < NT; ++nt) {
        const int n0 = chunk * (BN * NT) + nt * BN;
        const int bG0 = n0 >> 4;              // block B group base (8 groups)

        // stage(kt, dstbase): each wave DMAs 6 of the 24 1KB chunks.
        // Slab layout: [A-hi 8KB][B-hi 8KB][B-lo 8KB].
        auto stage = [&](int kt, char* dstbase) {
            #pragma unroll
            for (int t = 0; t < 6; ++t) {
                const int c = w * 6 + t;
                const bool isA  = (c < 8);
                const bool isBh = (c >= 8) && (c < 16);
                const u16* sp = isA ? qhi : (isBh ? khi : klo);
                const int idx = isA ? c : (isBh ? (c - 8) : (c - 16));
                const int gg  = (isA ? aG0 : bG0) + idx;
                const int grp = isA ? QG : KG;
                const size_t cb = ((size_t)kt * grp + gg) * 512 + lane * 8;
                g2l16(sp + cb, dstbase + c * 1024);
            }
        };

        __syncthreads();                      // scan reads of prev tile done
        stage(0, smem);                       // prologue: slab kt=0 -> buf0

        f4 acc[4][4];
        #pragma unroll
        for (int i = 0; i < 4; ++i)
            #pragma unroll
            for (int j = 0; j < 4; ++j) acc[i][j] = zf;

        for (int kt = 0; kt < KTOT; ++kt) {
            const int cur = kt & 1;
            __syncthreads();                  // drains vmcnt(0): buf[cur] ready

            // A-lo frags direct from global (L2), issued FIRST so the
            // compiler's wait for them is vmcnt(8) (prefetch stays in flight)
            short8 al[4];
            {
                const size_t ab = ((size_t)kt * QG + aG0w) * 512 + lane * 8;
                #pragma unroll
                for (int i = 0; i < 4; ++i)
                    al[i] = *(const short8*)(qlo + ab + i * 512);
            }

            if (kt + 1 < KTOT)                // issue kt+1 -> buf[1-cur]
                stage(kt + 1, smem + (1 - cur) * 24576);

            const char* cbuf = smem + cur * 24576;

            short8 ah[4], bhk[4];
            #pragma unroll
            for (int i = 0; i < 4; ++i)
                ah[i] = *(const short8*)(cbuf + (wm * 4 + i) * 1024 + lane * 16);
            // phase A: 32 MFMAs using only LDS operands (ah x bh, ah x bl)
            #pragma unroll
            for (int j = 0; j < 4; ++j) {
                bhk[j] = *(const short8*)(cbuf + 8192 + (wn * 4 + j) * 1024 + lane * 16);
                short8 bl = *(const short8*)(cbuf + 16384 + (wn * 4 + j) * 1024 + lane * 16);
                #pragma unroll
                for (int i = 0; i < 4; ++i) {
                    acc[i][j] = __builtin_amdgcn_mfma_f32_16x16x32_bf16(ah[i], bhk[j], acc[i][j], 0, 0, 0);
                    acc[i][j] = __builtin_amdgcn_mfma_f32_16x16x32_bf16(ah[i], bl, acc[i][j], 0, 0, 0);
                }
            }
            // phase B: 16 MFMAs consuming al (global loads now landed)
            #pragma unroll
            for (int j = 0; j < 4; ++j)
                #pragma unroll
                for (int i = 0; i < 4; ++i)
                    acc[i][j] = __builtin_amdgcn_mfma_f32_16x16x32_bf16(al[i], bhk[j], acc[i][j], 0, 0, 0);
        }

        // epilogue: dump raw acc (== sim) to LDS in two 64-col halves, scan rows
        const int srow = tid >> 1;
        const int c0 = (tid & 1) * 32;
        #pragma unroll 1
        for (int h = 0; h < 2; ++h) {
            __syncthreads();
            if (wn == h) {
                #pragma unroll
                for (int i = 0; i < 4; ++i)
                    #pragma unroll
                    for (int j = 0; j < 4; ++j)
                        #pragma unroll
                        for (int p = 0; p < 4; ++p)
                            scan[wm*64 + i*16 + quad*4 + p][j*16 + l16] = acc[i][j][p];
            }
            __syncthreads();
            const int gbase = n0 + h * 64 + c0;
            #pragma unroll
            for (int u = 0; u < 8; ++u) {
                const f4 v = *(const f4*)&scan[srow][c0 + 4*u];
                #pragma unroll
                for (int e = 0; e < 4; ++e) {
                    const float sv = v[e];
                    const int gi = gbase + 4*u + e;
                    r_sum += sv;
                    r_sq = fmaf(sv, sv, r_sq);
                    if (sv > r_m1)      { r_m2 = r_m1; r_i2 = r_i1; r_m1 = sv; r_i1 = gi; }
                    else if (sv > r_m2) { r_m2 = sv; r_i2 = gi; }
                }
            }
        }
    }

    // merge even/odd thread (same row, disjoint cols), write chunk partials
    __syncthreads();
    float* mb = (float*)smem;
    mb[tid*6+0] = r_sum; mb[tid*6+1] = r_sq;
    mb[tid*6+2] = r_m1;  mb[tid*6+3] = __int_as_float(r_i1);
    mb[tid*6+4] = r_m2;  mb[tid*6+5] = __int_as_float(r_i2);
    __syncthreads();
    if ((tid & 1) == 0) {
        const float* o = mb + (size_t)(tid + 1) * 6;
        const float bs = o[0], bq = o[1], bm1 = o[2], bm2 = o[4];
        const int bi1 = __float_as_int(o[3]), bi2 = __float_as_int(o[5]);
        float s = r_sum + bs, q2 = r_sq + bq;
        float m1 = r_m1, m2 = r_m2; int i1 = r_i1, i2 = r_i2;
        if (bm1 > m1 || (bm1 == m1 && bi1 < i1)) {
            float nm2; int ni2;
            if (m1 > bm2 || (m1 == bm2 && i1 < bi2)) { nm2 = m1; ni2 = i1; }
            else                                     { nm2 = bm2; ni2 = bi2; }
            m1 = bm1; i1 = bi1; m2 = nm2; i2 = ni2;
        } else if (bm1 > m2 || (bm1 == m2 && bi1 < i2)) {
            m2 = bm1; i2 = bi1;
        }
        const int row = b0 + (tid >> 1);
        float* p = partials + ((size_t)row * NCHUNK + chunk) * 8;
        f4 p0 = {s, q2, m1, __int_as_float(i1)};
        f4 p1 = {m2, __int_as_float(i2), 0.f, 0.f};
        *(f4*)p = p0;
        *(f4*)(p + 4) = p1;
    }
}

// ---------------------------------------------------------------------------
// Kernel 3: per-row merge of chunk partials; fp64 exact rescue of top-2;
// var accumulation; gather values[winner]. One wave per row.
// ---------------------------------------------------------------------------
__global__ __launch_bounds__(64) void finalize_kernel(
    const float* __restrict__ partials,
    const float* __restrict__ qg, const float* __restrict__ kg,
    const float* __restrict__ values,
    const float* __restrict__ invq, const float* __restrict__ invk,
    float* __restrict__ out)
{
    const int b = blockIdx.x;
    const int lane = threadIdx.x;

    float s = 0.f, q2 = 0.f, m1 = -INFINITY, m2 = -INFINITY;
    int i1 = 0x7fffffff, i2 = 0x7fffffff;
    #pragma unroll
    for (int cc = 0; cc < NCHUNK / 64; ++cc) {
        const int c = lane + cc * 64;
        const float* p = partials + ((size_t)b * NCHUNK + c) * 8;
        const float bs = p[0], bq = p[1], bm1 = p[2], bm2 = p[4];
        const int bi1 = __float_as_int(p[3]), bi2 = __float_as_int(p[5]);
        s += bs; q2 += bq;
        if (bm1 > m1 || (bm1 == m1 && bi1 < i1)) {
            float nm2; int ni2;
            if (m1 > bm2 || (m1 == bm2 && i1 < bi2)) { nm2 = m1; ni2 = i1; }
            else                                     { nm2 = bm2; ni2 = bi2; }
            m1 = bm1; i1 = bi1; m2 = nm2; i2 = ni2;
        } else if (bm1 > m2 || (bm1 == m2 && bi1 < i2)) {
            m2 = bm1; i2 = bi1;
        }
    }
    #pragma unroll
    for (int msk = 1; msk < 64; msk <<= 1) {
        const float bs = __shfl_xor(s, msk), bq = __shfl_xor(q2, msk);
        const float bm1 = __shfl_xor(m1, msk), bm2 = __shfl_xor(m2, msk);
        const int bi1 = __shfl_xor(i1, msk), bi2 = __shfl_xor(i2, msk);
        s += bs; q2 += bq;
        if (bm1 > m1 || (bm1 == m1 && bi1 < i1)) {
            float nm2; int ni2;
            if (m1 > bm2 || (m1 == bm2 && i1 < bi2)) { nm2 = m1; ni2 = i1; }
            else                                     { nm2 = bm2; ni2 = bi2; }
            m1 = bm1; i1 = bi1; m2 = nm2; i2 = ni2;
        } else if (bm1 > m2 || (bm1 == m2 && bi1 < i2)) {
            m2 = bm1; i2 = bi1;
        }
    }
    if (lane == 0) {
        const float var = (q2 - s * s / (float)N_) / (float)(N_ - 1);
        atomicAdd(out + (size_t)B_ * D_, var * (1.0f / B_));
    }

    // exact fp64 recompute of both candidates (deterministic tie-break)
    const float* qrow = qg + (size_t)b * D_;
    const float* k1 = kg + (size_t)i1 * D_;
    const float* k2 = kg + (size_t)i2 * D_;
    double d1 = 0.0, d2 = 0.0;
    #pragma unroll
    for (int v4 = 0; v4 < 4; ++v4) {
        const int off = v4 * 256 + lane * 4;
        const f4 qv = *(const f4*)(qrow + off);
        const f4 a1 = *(const f4*)(k1 + off);
        const f4 a2 = *(const f4*)(k2 + off);
        #pragma unroll
        for (int e = 0; e < 4; ++e) {
            d1 += (double)qv[e] * (double)a1[e];
            d2 += (double)qv[e] * (double)a2[e];
        }
    }
    #pragma unroll
    for (int msk = 1; msk < 64; msk <<= 1) {
        d1 += __shfl_xor(d1, msk);
        d2 += __shfl_xor(d2, msk);
    }
    const double sc = (double)invq[b];
    const double s1 = d1 * sc * (double)invk[i1];
    const double s2 = d2 * sc * (double)invk[i2];
    const int winner = (s2 > s1 || (s2 == s1 && i2 < i1)) ? i2 : i1;

    const float* vrow = values + (size_t)winner * D_;
    float* orow = out + (size_t)b * D_;
    #pragma unroll
    for (int v4 = 0; v4 < 4; ++v4) {
        const int off = v4 * 256 + lane * 4;
        *(f4*)(orow + off) = *(const f4*)(vrow + off);
    }
}

// ---------------------------------------------------------------------------
extern "C" void kernel_launch(void* const* d_in, const int* in_sizes, int n_in,
                              void* d_out, int out_size, void* d_ws, size_t ws_size,
                              hipStream_t stream)
{
    const float* q = (const float*)d_in[0];   // [B, D]
    const float* k = (const float*)d_in[1];   // [N, D]
    const float* v = (const float*)d_in[2];   // [N, D]
    float* out = (float*)d_out;               // [B*D retrieved | 1 var]
    float* ws = (float*)d_ws;

    float* invq = ws;                                          // 4096 f
    float* invk = ws + B_;                                     // 32768 f
    float* partials = ws + B_ + N_;                            // 4096*128*8 f (16 MB)
    u16* qhi = (u16*)(partials + (size_t)B_ * NCHUNK * 8);     // 8 MB packed
    u16* qlo = qhi + (size_t)B_ * D_;                          // 8 MB
    u16* khi = qlo + (size_t)B_ * D_;                          // 64 MB
    u16* klo = khi + (size_t)N_ * D_;                          // 64 MB

    pack_kernel<<<(B_ + N_) / 16, 256, 0, stream>>>(q, k, invq, invk, qhi, qlo, khi, klo, out);
    sim_stats_kernel<<<dim3(B_ / BM, NCHUNK), 256, 0, stream>>>(qhi, qlo, khi, klo, partials);
    finalize_kernel<<<B_, 64, 0, stream>>>(partials, q, k, v, invq, invk, out);
}

// Round 6
// 935.268 us; speedup vs baseline: 1.8745x; 1.8745x over previous
//
#include <hip/hip_runtime.h>
#include <math.h>
#include <stdint.h>

#define B_ 4096
#define N_ 32768
#define D_ 1024

#define BM 128
#define BN 128
#define NT 2
#define NCHUNK 128     // N_ / (BN*NT)
#define KTOT 32        // D_ / 32
#define QG (B_ / 16)   // 256 q-row groups
#define KG (N_ / 16)   // 2048 k-row groups

typedef __attribute__((ext_vector_type(8))) short short8;
typedef __attribute__((ext_vector_type(4))) float f4;
typedef unsigned short u16;

__device__ __forceinline__ u16 bf16_rn(float x) {
    uint32_t u = __float_as_uint(x);
    u += 0x7fffu + ((u >> 16) & 1u);
    return (u16)(u >> 16);
}

// fp32 -> (hi, lo) bf16 pair, both RN. Dropped residual ~2^-18 |x|.
__device__ __forceinline__ void split4(f4 v, uint2& hpack, uint2& lpack) {
    u16 h[4], l[4];
    #pragma unroll
    for (int e = 0; e < 4; ++e) {
        float x = v[e];
        u16 hb = bf16_rn(x);
        float hf = __uint_as_float(((uint32_t)hb) << 16);
        h[e] = hb;
        l[e] = bf16_rn(x - hf);
    }
    hpack.x = (uint32_t)h[0] | ((uint32_t)h[1] << 16);
    hpack.y = (uint32_t)h[2] | ((uint32_t)h[3] << 16);
    lpack.x = (uint32_t)l[0] | ((uint32_t)l[1] << 16);
    lpack.y = (uint32_t)l[2] | ((uint32_t)l[3] << 16);
}

// async global -> LDS, 16B per lane. LDS dest is wave-uniform base + lane*16.
__device__ __forceinline__ void g2l16(const void* g, void* l) {
    __builtin_amdgcn_global_load_lds(
        (const __attribute__((address_space(1))) char*)(uintptr_t)g,
        (__attribute__((address_space(3))) char*)(uint32_t)(uintptr_t)l,
        16, 0, 0);
}

// ---------------------------------------------------------------------------
// Kernel 1 (fused norm + pack, VERIFIED rounds 1/3): each thread loads exactly
// the 64 floats it will pack (kept in registers), block computes the 16 row
// inv-norms via shfl + a 4x16 LDS patch, then normalizes + splits into bf16
// hi/lo planes, packed FRAG-LINEAR: chunk(kt, g) = 1KB covering rows
// 16g..16g+15, k = 32kt..32kt+31, MFMA lane order: lane l holds
// (m = l&15, k = (l>>4)*8 + 0..7), 16B/lane.
// Plane layout: [kt][group][512 u16]. Also zeroes the var slot of d_out.
// ---------------------------------------------------------------------------
__global__ __launch_bounds__(256) void pack_kernel(
    const float* __restrict__ q, const float* __restrict__ k,
    float* __restrict__ invq, float* __restrict__ invk,
    u16* __restrict__ qhi, u16* __restrict__ qlo,
    u16* __restrict__ khi, u16* __restrict__ klo,
    float* __restrict__ out)
{
    const int g = blockIdx.x;                 // 0..(B_+N_)/16-1
    const int lane = threadIdx.x & 63;
    const int w = threadIdx.x >> 6;

    const float* src; float* invdst;
    u16 *dhi, *dlo; int groups, gg;
    if (g < B_ / 16) { src = q; invdst = invq; dhi = qhi; dlo = qlo; groups = QG; gg = g; }
    else { src = k; invdst = invk; dhi = khi; dlo = klo; groups = KG; gg = g - B_ / 16; }

    const int row = gg * 16 + (lane & 15);
    const int kofs = (lane >> 4) * 8;
    const float* rp = src + (size_t)row * D_;

    // phase 1: load this thread's 64 elements (8 kts), partial sum-of-squares
    f4 v0[8], v1[8];
    float s = 0.f;
    #pragma unroll
    for (int u = 0; u < 8; ++u) {
        const int kt = w + u * 4;
        v0[u] = *(const f4*)(rp + kt * 32 + kofs);
        v1[u] = *(const f4*)(rp + kt * 32 + kofs + 4);
        #pragma unroll
        for (int e = 0; e < 4; ++e) {
            s = fmaf(v0[u][e], v0[u][e], s);
            s = fmaf(v1[u][e], v1[u][e], s);
        }
    }
    // reduce over the 4 quads of this wave (same l16 = same row)
    s += __shfl_xor(s, 16);
    s += __shfl_xor(s, 32);
    __shared__ float red[4][16];
    if ((lane >> 4) == 0) red[w][lane & 15] = s;
    __syncthreads();
    const float tot = red[0][lane & 15] + red[1][lane & 15]
                    + red[2][lane & 15] + red[3][lane & 15];
    const float scale = 1.0f / fmaxf(sqrtf(tot), 1e-12f);
    if (w == 0 && lane < 16) invdst[gg * 16 + lane] = scale;

    // phase 2: scale + split + frag-linear store (data still in registers)
    #pragma unroll
    for (int u = 0; u < 8; ++u) {
        const int kt = w + u * 4;
        f4 a = v0[u] * scale, b = v1[u] * scale;
        uint2 h0, l0, h1, l1;
        split4(a, h0, l0);
        split4(b, h1, l1);
        const size_t cbase = ((size_t)kt * groups + gg) * 512 + lane * 8;
        uint4 hh = {h0.x, h0.y, h1.x, h1.y};
        uint4 ll = {l0.x, l0.y, l1.x, l1.y};
        *(uint4*)(dhi + cbase) = hh;
        *(uint4*)(dlo + cbase) = ll;
    }
    if (g == 0 && threadIdx.x == 0) out[(size_t)B_ * D_] = 0.0f;
}

// ---------------------------------------------------------------------------
// Kernel 2: split-bf16 MFMA sim GEMM, 16x16x32, PHASE-SPLIT kt.
// Each kt is two phases with half-size (16KB) slabs in two FIXED buffers:
//   P1 (buf0): {A-hi, B-hi} -> read ah[4], bh[4]; 16 MFMA (ah x bh)
//   P2 (buf1): {A-lo, B-lo} -> 32 MFMA (ah x bl, al x bh), al/bl transient
// Every barrier drains the DMAs filling the OTHER buffer (same drain
// discipline as the verified R0/R3 template, at half granularity). ah/bh
// persist in registers across the mid-kt barrier (LDS-sourced, no vmcnt
// hazard). All operands from LDS -> low reg pressure (~60 VGPR + 64 AGPR),
// no spill. LDS/block 34816 -> 3 blocks/CU (12 waves): finer barriers +
// more independent blocks interleave the drain bubbles.
// ---------------------------------------------------------------------------
__global__ __launch_bounds__(256, 3) void sim_stats_kernel(
    const u16* __restrict__ qhi, const u16* __restrict__ qlo,
    const u16* __restrict__ khi, const u16* __restrict__ klo,
    float* __restrict__ partials)
{
    __shared__ __align__(16) char smem[34816];   // 2 x 16KB half-slabs; scan aliased

    const int tid = threadIdx.x;
    const int lane = tid & 63;
    const int w = tid >> 6;
    const int wm = w >> 1, wn = w & 1;
    const int quad = lane >> 4;
    const int l16 = lane & 15;
    const int mtile = blockIdx.x;
    const int chunk = blockIdx.y;
    const int b0 = mtile * BM;

    const u16* p1base = (w < 2) ? qhi : khi;   // hi planes
    const u16* p2base = (w < 2) ? qlo : klo;   // lo planes
    const int grpw = (w < 2) ? QG : KG;
    const int aG0 = b0 >> 4;

    char* const buf0 = smem;             // P1 half: [A-hi 8KB][B-hi 8KB]
    char* const buf1 = smem + 16384;     // P2 half: [A-lo 8KB][B-lo 8KB]
    char* const dstw0 = buf0 + w * 4096; // this wave's 4 chunks
    char* const dstw1 = buf1 + w * 4096;

    float (*scan)[68] = (float(*)[68])smem;

    float r_sum = 0.f, r_sq = 0.f, r_m1 = -INFINITY, r_m2 = -INFINITY;
    int r_i1 = 0x7fffffff, r_i2 = 0x7fffffff;

    const f4 zf = {0.f, 0.f, 0.f, 0.f};

    for (int nt = 0; nt < NT; ++nt) {
        const int n0 = chunk * (BN * NT) + nt * BN;
        // this wave's 4-group base within its plane
        const int gw0 = ((w < 2) ? aG0 : (n0 >> 4)) + (w & 1) * 4;

        __syncthreads();                      // scan reads of prev tile done
        // prologue: stage P1(kt=0) -> buf0
        {
            const size_t cb = ((size_t)gw0) * 512 + lane * 8;
            #pragma unroll
            for (int t = 0; t < 4; ++t)
                g2l16(p1base + cb + t * 512, dstw0 + t * 1024);
        }

        f4 acc[4][4];
        #pragma unroll
        for (int i = 0; i < 4; ++i)
            #pragma unroll
            for (int j = 0; j < 4; ++j) acc[i][j] = zf;

        for (int kt = 0; kt < KTOT; ++kt) {
            // ---- phase 1 ----
            __syncthreads();                  // P1(kt) DMAs drained
            {   // issue P2(kt) -> buf1
                const size_t cb = ((size_t)kt * grpw + gw0) * 512 + lane * 8;
                #pragma unroll
                for (int t = 0; t < 4; ++t)
                    g2l16(p2base + cb + t * 512, dstw1 + t * 1024);
            }
            short8 ah[4], bh[4];
            #pragma unroll
            for (int i = 0; i < 4; ++i) {
                ah[i] = *(const short8*)(buf0 + (wm * 4 + i) * 1024 + lane * 16);
                bh[i] = *(const short8*)(buf0 + 8192 + (wn * 4 + i) * 1024 + lane * 16);
            }
            #pragma unroll
            for (int j = 0; j < 4; ++j)
                #pragma unroll
                for (int i = 0; i < 4; ++i)
                    acc[i][j] = __builtin_amdgcn_mfma_f32_16x16x32_bf16(ah[i], bh[j], acc[i][j], 0, 0, 0);

            // ---- phase 2 ----
            __syncthreads();                  // P2(kt) DMAs drained
            if (kt + 1 < KTOT) {              // issue P1(kt+1) -> buf0
                const size_t cb = ((size_t)(kt + 1) * grpw + gw0) * 512 + lane * 8;
                #pragma unroll
                for (int t = 0; t < 4; ++t)
                    g2l16(p1base + cb + t * 512, dstw0 + t * 1024);
            }
            #pragma unroll
            for (int j = 0; j < 4; ++j) {
                const short8 bl = *(const short8*)(buf1 + 8192 + (wn * 4 + j) * 1024 + lane * 16);
                #pragma unroll
                for (int i = 0; i < 4; ++i)
                    acc[i][j] = __builtin_amdgcn_mfma_f32_16x16x32_bf16(ah[i], bl, acc[i][j], 0, 0, 0);
            }
            #pragma unroll
            for (int i = 0; i < 4; ++i) {
                const short8 al = *(const short8*)(buf1 + (wm * 4 + i) * 1024 + lane * 16);
                #pragma unroll
                for (int j = 0; j < 4; ++j)
                    acc[i][j] = __builtin_amdgcn_mfma_f32_16x16x32_bf16(al, bh[j], acc[i][j], 0, 0, 0);
            }
        }

        // epilogue: dump raw acc (== sim) to LDS in two 64-col halves, scan rows
        const int srow = tid >> 1;
        const int c0 = (tid & 1) * 32;
        #pragma unroll 1
        for (int h = 0; h < 2; ++h) {
            __syncthreads();
            if (wn == h) {
                #pragma unroll
                for (int i = 0; i < 4; ++i)
                    #pragma unroll
                    for (int j = 0; j < 4; ++j)
                        #pragma unroll
                        for (int p = 0; p < 4; ++p)
                            scan[wm*64 + i*16 + quad*4 + p][j*16 + l16] = acc[i][j][p];
            }
            __syncthreads();
            const int gbase = n0 + h * 64 + c0;
            #pragma unroll
            for (int u = 0; u < 8; ++u) {
                const f4 v = *(const f4*)&scan[srow][c0 + 4*u];
                #pragma unroll
                for (int e = 0; e < 4; ++e) {
                    const float sv = v[e];
                    const int gi = gbase + 4*u + e;
                    r_sum += sv;
                    r_sq = fmaf(sv, sv, r_sq);
                    if (sv > r_m1)      { r_m2 = r_m1; r_i2 = r_i1; r_m1 = sv; r_i1 = gi; }
                    else if (sv > r_m2) { r_m2 = sv; r_i2 = gi; }
                }
            }
        }
    }

    // merge even/odd thread (same row, disjoint cols), write chunk partials
    __syncthreads();
    float* mb = (float*)smem;
    mb[tid*6+0] = r_sum; mb[tid*6+1] = r_sq;
    mb[tid*6+2] = r_m1;  mb[tid*6+3] = __int_as_float(r_i1);
    mb[tid*6+4] = r_m2;  mb[tid*6+5] = __int_as_float(r_i2);
    __syncthreads();
    if ((tid & 1) == 0) {
        const float* o = mb + (size_t)(tid + 1) * 6;
        const float bs = o[0], bq = o[1], bm1 = o[2], bm2 = o[4];
        const int bi1 = __float_as_int(o[3]), bi2 = __float_as_int(o[5]);
        float s = r_sum + bs, q2 = r_sq + bq;
        float m1 = r_m1, m2 = r_m2; int i1 = r_i1, i2 = r_i2;
        if (bm1 > m1 || (bm1 == m1 && bi1 < i1)) {
            float nm2; int ni2;
            if (m1 > bm2 || (m1 == bm2 && i1 < bi2)) { nm2 = m1; ni2 = i1; }
            else                                     { nm2 = bm2; ni2 = bi2; }
            m1 = bm1; i1 = bi1; m2 = nm2; i2 = ni2;
        } else if (bm1 > m2 || (bm1 == m2 && bi1 < i2)) {
            m2 = bm1; i2 = bi1;
        }
        const int row = b0 + (tid >> 1);
        float* p = partials + ((size_t)row * NCHUNK + chunk) * 8;
        f4 p0 = {s, q2, m1, __int_as_float(i1)};
        f4 p1 = {m2, __int_as_float(i2), 0.f, 0.f};
        *(f4*)p = p0;
        *(f4*)(p + 4) = p1;
    }
}

// ---------------------------------------------------------------------------
// Kernel 3: per-row merge of chunk partials; fp64 exact rescue of top-2;
// var accumulation; gather values[winner]. One wave per row.
// ---------------------------------------------------------------------------
__global__ __launch_bounds__(64) void finalize_kernel(
    const float* __restrict__ partials,
    const float* __restrict__ qg, const float* __restrict__ kg,
    const float* __restrict__ values,
    const float* __restrict__ invq, const float* __restrict__ invk,
    float* __restrict__ out)
{
    const int b = blockIdx.x;
    const int lane = threadIdx.x;

    float s = 0.f, q2 = 0.f, m1 = -INFINITY, m2 = -INFINITY;
    int i1 = 0x7fffffff, i2 = 0x7fffffff;
    #pragma unroll
    for (int cc = 0; cc < NCHUNK / 64; ++cc) {
        const int c = lane + cc * 64;
        const float* p = partials + ((size_t)b * NCHUNK + c) * 8;
        const float bs = p[0], bq = p[1], bm1 = p[2], bm2 = p[4];
        const int bi1 = __float_as_int(p[3]), bi2 = __float_as_int(p[5]);
        s += bs; q2 += bq;
        if (bm1 > m1 || (bm1 == m1 && bi1 < i1)) {
            float nm2; int ni2;
            if (m1 > bm2 || (m1 == bm2 && i1 < bi2)) { nm2 = m1; ni2 = i1; }
            else                                     { nm2 = bm2; ni2 = bi2; }
            m1 = bm1; i1 = bi1; m2 = nm2; i2 = ni2;
        } else if (bm1 > m2 || (bm1 == m2 && bi1 < i2)) {
            m2 = bm1; i2 = bi1;
        }
    }
    #pragma unroll
    for (int msk = 1; msk < 64; msk <<= 1) {
        const float bs = __shfl_xor(s, msk), bq = __shfl_xor(q2, msk);
        const float bm1 = __shfl_xor(m1, msk), bm2 = __shfl_xor(m2, msk);
        const int bi1 = __shfl_xor(i1, msk), bi2 = __shfl_xor(i2, msk);
        s += bs; q2 += bq;
        if (bm1 > m1 || (bm1 == m1 && bi1 < i1)) {
            float nm2; int ni2;
            if (m1 > bm2 || (m1 == bm2 && i1 < bi2)) { nm2 = m1; ni2 = i1; }
            else                                     { nm2 = bm2; ni2 = bi2; }
            m1 = bm1; i1 = bi1; m2 = nm2; i2 = ni2;
        } else if (bm1 > m2 || (bm1 == m2 && bi1 < i2)) {
            m2 = bm1; i2 = bi1;
        }
    }
    if (lane == 0) {
        const float var = (q2 - s * s / (float)N_) / (float)(N_ - 1);
        atomicAdd(out + (size_t)B_ * D_, var * (1.0f / B_));
    }

    // exact fp64 recompute of both candidates (deterministic tie-break)
    const float* qrow = qg + (size_t)b * D_;
    const float* k1 = kg + (size_t)i1 * D_;
    const float* k2 = kg + (size_t)i2 * D_;
    double d1 = 0.0, d2 = 0.0;
    #pragma unroll
    for (int v4 = 0; v4 < 4; ++v4) {
        const int off = v4 * 256 + lane * 4;
        const f4 qv = *(const f4*)(qrow + off);
        const f4 a1 = *(const f4*)(k1 + off);
        const f4 a2 = *(const f4*)(k2 + off);
        #pragma unroll
        for (int e = 0; e < 4; ++e) {
            d1 += (double)qv[e] * (double)a1[e];
            d2 += (double)qv[e] * (double)a2[e];
        }
    }
    #pragma unroll
    for (int msk = 1; msk < 64; msk <<= 1) {
        d1 += __shfl_xor(d1, msk);
        d2 += __shfl_xor(d2, msk);
    }
    const double sc = (double)invq[b];
    const double s1 = d1 * sc * (double)invk[i1];
    const double s2 = d2 * sc * (double)invk[i2];
    const int winner = (s2 > s1 || (s2 == s1 && i2 < i1)) ? i2 : i1;

    const float* vrow = values + (size_t)winner * D_;
    float* orow = out + (size_t)b * D_;
    #pragma unroll
    for (int v4 = 0; v4 < 4; ++v4) {
        const int off = v4 * 256 + lane * 4;
        *(f4*)(orow + off) = *(const f4*)(vrow + off);
    }
}

// ---------------------------------------------------------------------------
extern "C" void kernel_launch(void* const* d_in, const int* in_sizes, int n_in,
                              void* d_out, int out_size, void* d_ws, size_t ws_size,
                              hipStream_t stream)
{
    const float* q = (const float*)d_in[0];   // [B, D]
    const float* k = (const float*)d_in[1];   // [N, D]
    const float* v = (const float*)d_in[2];   // [N, D]
    float* out = (float*)d_out;               // [B*D retrieved | 1 var]
    float* ws = (float*)d_ws;

    float* invq = ws;                                          // 4096 f
    float* invk = ws + B_;                                     // 32768 f
    float* partials = ws + B_ + N_;                            // 4096*128*8 f (16 MB)
    u16* qhi = (u16*)(partials + (size_t)B_ * NCHUNK * 8);     // 8 MB packed
    u16* qlo = qhi + (size_t)B_ * D_;                          // 8 MB
    u16* khi = qlo + (size_t)B_ * D_;                          // 64 MB
    u16* klo = khi + (size_t)N_ * D_;                          // 64 MB

    pack_kernel<<<(B_ + N_) / 16, 256, 0, stream>>>(q, k, invq, invk, qhi, qlo, khi, klo, out);
    sim_stats_kernel<<<dim3(B_ / BM, NCHUNK), 256, 0, stream>>>(qhi, qlo, khi, klo, partials);
    finalize_kernel<<<B_, 64, 0, stream>>>(partials, q, k, v, invq, invk, out);
}